// Round 1
// baseline (235.665 us; speedup 1.0000x reference)
//
#include <hip/hip_runtime.h>
#include <hip/hip_bf16.h>
#include <stdint.h>

// ---------- types ----------
typedef __attribute__((ext_vector_type(8))) short short8;     // 8 bf16 (4 VGPRs) MFMA A/B frag
typedef __attribute__((ext_vector_type(4))) float f32x4;      // MFMA C/D frag
typedef __attribute__((ext_vector_type(4))) unsigned short us4;

static __device__ __forceinline__ unsigned short f2bf(float f) {
    union { float f; uint32_t u; } v; v.f = f;
    uint32_t u = v.u;
    uint32_t r = u + 0x7FFFu + ((u >> 16) & 1u);   // round-to-nearest-even
    return (unsigned short)(r >> 16);
}
static __device__ __forceinline__ float bf2f(unsigned short h) {
    union { uint32_t u; float f; } v; v.u = ((uint32_t)h) << 16;
    return v.f;
}

// ---------- kernel 0: W1 (1024x1024 f32) -> bf16 ----------
__global__ __launch_bounds__(256) void convert_w1(const float* __restrict__ w,
                                                  unsigned short* __restrict__ o) {
    int idx = blockIdx.x * 256 + threadIdx.x;      // 262144 threads, 4 elems each
    const float4* w4 = (const float4*)w;
    float4 v = w4[idx];
    us4 r = { f2bf(v.x), f2bf(v.y), f2bf(v.z), f2bf(v.w) };
    *(us4*)&o[(size_t)idx * 4] = r;
}

// ---------- kernel 1: cb[row] = sum_n (x@W2^T + b2)*(x@W3^T + b3), + x -> bf16 ----------
// grid 128 blocks x 256 threads; block covers 64 rows (4 waves x 16 rows)
__global__ __launch_bounds__(256) void cb_kernel(
    const float* __restrict__ x,          // [8192][1024]
    const float* __restrict__ W2,         // [16][1024]
    const float* __restrict__ b2,         // [16]
    const float* __restrict__ W3,         // [16][1024]
    const float* __restrict__ b3,         // [16]
    unsigned short* __restrict__ xb,      // out: [8192][1024] bf16
    float* __restrict__ cbo)              // out: [8192]
{
    __shared__ unsigned short w2s[16 * 1024];
    __shared__ unsigned short w3s[16 * 1024];
    const int t = threadIdx.x;

    // stage W2/W3 as bf16 into LDS (16384 f32 each; 64 elems/thread each)
    for (int p = 0; p < 16; ++p) {
        int idx = t * 4 + p * 1024;
        float4 v2 = *(const float4*)&W2[idx];
        float4 v3 = *(const float4*)&W3[idx];
        us4 o2 = { f2bf(v2.x), f2bf(v2.y), f2bf(v2.z), f2bf(v2.w) };
        us4 o3 = { f2bf(v3.x), f2bf(v3.y), f2bf(v3.z), f2bf(v3.w) };
        *(us4*)&w2s[idx] = o2;
        *(us4*)&w3s[idx] = o3;
    }
    __syncthreads();

    const int wave = t >> 6, lane = t & 63;

    for (int r = 0; r < 16; ++r) {
        const int row = blockIdx.x * 64 + wave * 16 + r;
        const size_t rb = (size_t)row * 1024;
        // load full x row across the wave: lane holds k = lane*4 + c*256 .. +3
        float4 xr[4];
#pragma unroll
        for (int c = 0; c < 4; ++c)
            xr[c] = *(const float4*)&x[rb + lane * 4 + c * 256];
        // write bf16 copy of x
#pragma unroll
        for (int c = 0; c < 4; ++c) {
            us4 o = { f2bf(xr[c].x), f2bf(xr[c].y), f2bf(xr[c].z), f2bf(xr[c].w) };
            *(us4*)&xb[rb + lane * 4 + c * 256] = o;
        }
        float Ba[16], Ca[16];
#pragma unroll
        for (int n = 0; n < 16; ++n) {
            float bs = 0.f, cs = 0.f;
#pragma unroll
            for (int c = 0; c < 4; ++c) {
                int k = lane * 4 + c * 256;
                us4 w2v = *(const us4*)&w2s[n * 1024 + k];
                us4 w3v = *(const us4*)&w3s[n * 1024 + k];
                bs += xr[c].x * bf2f(w2v.x) + xr[c].y * bf2f(w2v.y)
                    + xr[c].z * bf2f(w2v.z) + xr[c].w * bf2f(w2v.w);
                cs += xr[c].x * bf2f(w3v.x) + xr[c].y * bf2f(w3v.y)
                    + xr[c].z * bf2f(w3v.z) + xr[c].w * bf2f(w3v.w);
            }
            Ba[n] = bs; Ca[n] = cs;
        }
        // wave butterfly reduce (64 lanes)
#pragma unroll
        for (int off = 32; off > 0; off >>= 1) {
#pragma unroll
            for (int n = 0; n < 16; ++n) {
                Ba[n] += __shfl_xor(Ba[n], off, 64);
                Ca[n] += __shfl_xor(Ca[n], off, 64);
            }
        }
        if (lane == 0) {
            float s = 0.f;
#pragma unroll
            for (int n = 0; n < 16; ++n)
                s += (Ba[n] + b2[n]) * (Ca[n] + b3[n]);
            cbo[row] = s;
        }
    }
}

// ---------- kernel 2: delta GEMM + fused epilogue ----------
// y[r][c] = x[r][c] * softplus( sum_k xb[r][k]*w1b[c][k] + b1[c] ) * cb[r]
// 128x128 tile, BK=32, 256 threads = 4 waves (2x2), 16x16x32 bf16 MFMA
__global__ __launch_bounds__(256, 2) void gemm_kernel(
    const unsigned short* __restrict__ xb,   // [8192][1024] bf16
    const unsigned short* __restrict__ w1b,  // [1024][1024] bf16 (N x K)
    const float* __restrict__ b1,            // [1024]
    const float* __restrict__ x,             // [8192][1024] f32
    const float* __restrict__ cb,            // [8192]
    float* __restrict__ y)                   // [8192][1024] f32
{
    __shared__ unsigned short As[128 * 32];
    __shared__ unsigned short Bs[128 * 32];

    const int t = threadIdx.x;
    const int wid = t >> 6, lane = t & 63;
    const int wm = wid >> 1, wn = wid & 1;
    const int row0 = blockIdx.y * 128;
    const int col0 = blockIdx.x * 128;

    f32x4 acc[4][4];
#pragma unroll
    for (int m = 0; m < 4; ++m)
#pragma unroll
        for (int n = 0; n < 4; ++n)
            acc[m][n] = (f32x4){0.f, 0.f, 0.f, 0.f};

    const int srow = (wid << 4) + (lane >> 2);  // row within a 64-row pass
    const int kc = lane & 3;                    // 16B chunk within 64B row

    for (int kt = 0; kt < 1024; kt += 32) {
        __syncthreads();  // all waves done reading As/Bs of previous iter
#pragma unroll
        for (int p = 0; p < 2; ++p) {
            const int r = p * 64 + srow;
            const unsigned short* ga = &xb[(size_t)(row0 + r) * 1024 + kt + kc * 8];
            const unsigned short* gb = &w1b[(size_t)(col0 + r) * 1024 + kt + kc * 8];
            __builtin_amdgcn_global_load_lds(
                (const __attribute__((address_space(1))) void*)ga,
                (__attribute__((address_space(3))) void*)&As[r * 32 + kc * 8], 16, 0, 0);
            __builtin_amdgcn_global_load_lds(
                (const __attribute__((address_space(1))) void*)gb,
                (__attribute__((address_space(3))) void*)&Bs[r * 32 + kc * 8], 16, 0, 0);
        }
        __syncthreads();  // compiler drains vmcnt before s_barrier

        short8 af[4], bf[4];
        const int ro = lane & 15;
        const int ko = (lane >> 4) * 8;
#pragma unroll
        for (int m = 0; m < 4; ++m)
            af[m] = *(const short8*)&As[(wm * 64 + m * 16 + ro) * 32 + ko];
#pragma unroll
        for (int n = 0; n < 4; ++n)
            bf[n] = *(const short8*)&Bs[(wn * 64 + n * 16 + ro) * 32 + ko];
#pragma unroll
        for (int m = 0; m < 4; ++m)
#pragma unroll
            for (int n = 0; n < 4; ++n)
                acc[m][n] = __builtin_amdgcn_mfma_f32_16x16x32_bf16(af[m], bf[n], acc[m][n], 0, 0, 0);
    }

    // epilogue: C/D layout col=lane&15, row=(lane>>4)*4+j
#pragma unroll
    for (int m = 0; m < 4; ++m) {
        const int grow_base = row0 + wm * 64 + m * 16 + (lane >> 4) * 4;
#pragma unroll
        for (int n = 0; n < 4; ++n) {
            const int gcol = col0 + wn * 64 + n * 16 + (lane & 15);
            const float bv = b1[gcol];
#pragma unroll
            for (int j = 0; j < 4; ++j) {
                const int grow = grow_base + j;
                const float v = acc[m][n][j] + bv;
                const float sp = (v > 20.f) ? v : log1pf(expf(v));
                y[(size_t)grow * 1024 + gcol] = x[(size_t)grow * 1024 + gcol] * sp * cb[grow];
            }
        }
    }
}

extern "C" void kernel_launch(void* const* d_in, const int* in_sizes, int n_in,
                              void* d_out, int out_size, void* d_ws, size_t ws_size,
                              hipStream_t stream) {
    const float* x  = (const float*)d_in[0];
    const float* W1 = (const float*)d_in[1];
    const float* b1 = (const float*)d_in[2];
    const float* W2 = (const float*)d_in[3];
    const float* b2 = (const float*)d_in[4];
    const float* W3 = (const float*)d_in[5];
    const float* b3 = (const float*)d_in[6];
    // d_in[7] (A) is a dead parameter in the reference (multiplied by zeros)

    float* y = (float*)d_out;

    unsigned short* xb  = (unsigned short*)d_ws;                 // 16 MB
    unsigned short* w1b = xb + (size_t)8192 * 1024;              // 2 MB
    float* cbuf = (float*)(w1b + (size_t)1024 * 1024);           // 32 KB

    convert_w1<<<1024, 256, 0, stream>>>(W1, w1b);
    cb_kernel<<<128, 256, 0, stream>>>(x, W2, b2, W3, b3, xb, cbuf);
    gemm_kernel<<<dim3(8, 64), 256, 0, stream>>>(xb, w1b, b1, x, cbuf, y);
}

// Round 2
// 85.613 us; speedup vs baseline: 2.7527x; 2.7527x over previous
//
#include <hip/hip_runtime.h>
#include <hip/hip_bf16.h>
#include <stdint.h>

// ---------- types ----------
typedef __attribute__((ext_vector_type(8))) short short8;     // 8 bf16 (4 VGPRs) MFMA A/B frag
typedef __attribute__((ext_vector_type(4))) float f32x4;      // MFMA C/D frag
typedef __attribute__((ext_vector_type(4))) unsigned short us4;

static __device__ __forceinline__ unsigned short f2bf(float f) {
    union { float f; uint32_t u; } v; v.f = f;
    uint32_t u = v.u;
    uint32_t r = u + 0x7FFFu + ((u >> 16) & 1u);   // round-to-nearest-even
    return (unsigned short)(r >> 16);
}

static __device__ __forceinline__ short8 cvt8(float4 a, float4 b) {
    short8 r;
    r[0] = (short)f2bf(a.x); r[1] = (short)f2bf(a.y);
    r[2] = (short)f2bf(a.z); r[3] = (short)f2bf(a.w);
    r[4] = (short)f2bf(b.x); r[5] = (short)f2bf(b.y);
    r[6] = (short)f2bf(b.z); r[7] = (short)f2bf(b.w);
    return r;
}

// ---------- kernel 0: convert W1 / W2 / W3 f32 -> bf16 ----------
// blocks [0,1024): W1 (1M elems); [1024,1040): W2 (16K); [1040,1056): W3 (16K)
__global__ __launch_bounds__(256) void convert_w(const float* __restrict__ w1,
                                                 const float* __restrict__ w2,
                                                 const float* __restrict__ w3,
                                                 unsigned short* __restrict__ o1,
                                                 unsigned short* __restrict__ o2,
                                                 unsigned short* __restrict__ o3) {
    int b = blockIdx.x;
    const float* src; unsigned short* dst; int idx;
    if (b < 1024)      { src = w1; dst = o1; idx = b * 256 + threadIdx.x; }
    else if (b < 1040) { src = w2; dst = o2; idx = (b - 1024) * 256 + threadIdx.x; }
    else               { src = w3; dst = o3; idx = (b - 1040) * 256 + threadIdx.x; }
    float4 v = ((const float4*)src)[idx];
    us4 r = { f2bf(v.x), f2bf(v.y), f2bf(v.z), f2bf(v.w) };
    *(us4*)&dst[(size_t)idx * 4] = r;
}

// ---------- kernel 1: cb[row] = sum_n (x@W2^T + b2)*(x@W3^T + b3), + x -> bf16 ----------
// 512 blocks x 256 threads. Block = 16 rows; 4 waves split K (256 each).
// MFMA 16x16x32: A = x rows (converted in-register), B = W2/W3 bf16 rows.
__global__ __launch_bounds__(256) void cb_kernel(
    const float* __restrict__ x,            // [8192][1024]
    const unsigned short* __restrict__ w2b, // [16][1024] bf16
    const unsigned short* __restrict__ w3b, // [16][1024] bf16
    const float* __restrict__ b2,           // [16]
    const float* __restrict__ b3,           // [16]
    unsigned short* __restrict__ xb,        // out: [8192][1024] bf16
    float* __restrict__ cbo)                // out: [8192]
{
    __shared__ float red[4][2][16][16];     // [wave][B/C][row][n] = 8 KB

    const int t = threadIdx.x;
    const int wave = t >> 6, lane = t & 63;
    const int r0 = blockIdx.x * 16;
    const int rrow = lane & 15;             // row within tile (load phase)
    const int klane = (lane >> 4) * 8;      // k offset within 32-chunk
    const size_t xrow = (size_t)(r0 + rrow) * 1024;
    const int k0 = wave * 256;

    f32x4 accB = {0.f, 0.f, 0.f, 0.f};
    f32x4 accC = {0.f, 0.f, 0.f, 0.f};

#pragma unroll
    for (int ks = 0; ks < 256; ks += 32) {
        const int k = k0 + ks + klane;
        float4 xa = *(const float4*)&x[xrow + k];
        float4 xc = *(const float4*)&x[xrow + k + 4];
        short8 af = cvt8(xa, xc);
        *(short8*)&xb[xrow + k] = af;                                  // bf16 copy of x
        short8 w2f = *(const short8*)&w2b[(size_t)rrow * 1024 + k];    // n = rrow
        short8 w3f = *(const short8*)&w3b[(size_t)rrow * 1024 + k];
        accB = __builtin_amdgcn_mfma_f32_16x16x32_bf16(af, w2f, accB, 0, 0, 0);
        accC = __builtin_amdgcn_mfma_f32_16x16x32_bf16(af, w3f, accC, 0, 0, 0);
    }

    // C/D layout: col(n) = lane&15, row = (lane>>4)*4 + j
#pragma unroll
    for (int j = 0; j < 4; ++j) {
        red[wave][0][(lane >> 4) * 4 + j][lane & 15] = accB[j];
        red[wave][1][(lane >> 4) * 4 + j][lane & 15] = accC[j];
    }
    __syncthreads();

    if (wave == 0) {
        const int n = lane & 15;
        const float b2v = b2[n], b3v = b3[n];
        float prod[4];
#pragma unroll
        for (int j = 0; j < 4; ++j) {
            const int row = (lane >> 4) * 4 + j;
            float Bv = red[0][0][row][n] + red[1][0][row][n]
                     + red[2][0][row][n] + red[3][0][row][n] + b2v;
            float Cv = red[0][1][row][n] + red[1][1][row][n]
                     + red[2][1][row][n] + red[3][1][row][n] + b3v;
            prod[j] = Bv * Cv;
        }
#pragma unroll
        for (int off = 1; off < 16; off <<= 1)
#pragma unroll
            for (int j = 0; j < 4; ++j)
                prod[j] += __shfl_xor(prod[j], off, 64);
        if ((lane & 15) == 0) {
#pragma unroll
            for (int j = 0; j < 4; ++j)
                cbo[r0 + (lane >> 4) * 4 + j] = prod[j];
        }
    }
}

// ---------- kernel 2: delta GEMM + fused epilogue ----------
// y[r][c] = x[r][c] * softplus( sum_k xb[r][k]*w1b[c][k] + b1[c] ) * cb[r]
// 128x128 tile, BK=32, 256 threads = 4 waves (2x2), 16x16x32 bf16 MFMA
__global__ __launch_bounds__(256, 2) void gemm_kernel(
    const unsigned short* __restrict__ xb,   // [8192][1024] bf16
    const unsigned short* __restrict__ w1b,  // [1024][1024] bf16 (N x K)
    const float* __restrict__ b1,            // [1024]
    const float* __restrict__ x,             // [8192][1024] f32
    const float* __restrict__ cb,            // [8192]
    float* __restrict__ y)                   // [8192][1024] f32
{
    __shared__ unsigned short As[128 * 32];
    __shared__ unsigned short Bs[128 * 32];

    const int t = threadIdx.x;
    const int wid = t >> 6, lane = t & 63;
    const int wm = wid >> 1, wn = wid & 1;
    const int row0 = blockIdx.y * 128;
    const int col0 = blockIdx.x * 128;

    f32x4 acc[4][4];
#pragma unroll
    for (int m = 0; m < 4; ++m)
#pragma unroll
        for (int n = 0; n < 4; ++n)
            acc[m][n] = (f32x4){0.f, 0.f, 0.f, 0.f};

    const int srow = (wid << 4) + (lane >> 2);  // row within a 64-row pass
    const int kc = lane & 3;                    // 16B chunk within 64B row

    for (int kt = 0; kt < 1024; kt += 32) {
        __syncthreads();  // all waves done reading As/Bs of previous iter
#pragma unroll
        for (int p = 0; p < 2; ++p) {
            const int r = p * 64 + srow;
            const unsigned short* ga = &xb[(size_t)(row0 + r) * 1024 + kt + kc * 8];
            const unsigned short* gb = &w1b[(size_t)(col0 + r) * 1024 + kt + kc * 8];
            __builtin_amdgcn_global_load_lds(
                (const __attribute__((address_space(1))) void*)ga,
                (__attribute__((address_space(3))) void*)&As[r * 32 + kc * 8], 16, 0, 0);
            __builtin_amdgcn_global_load_lds(
                (const __attribute__((address_space(1))) void*)gb,
                (__attribute__((address_space(3))) void*)&Bs[r * 32 + kc * 8], 16, 0, 0);
        }
        __syncthreads();  // compiler drains vmcnt before s_barrier

        short8 af[4], bf[4];
        const int ro = lane & 15;
        const int ko = (lane >> 4) * 8;
#pragma unroll
        for (int m = 0; m < 4; ++m)
            af[m] = *(const short8*)&As[(wm * 64 + m * 16 + ro) * 32 + ko];
#pragma unroll
        for (int n = 0; n < 4; ++n)
            bf[n] = *(const short8*)&Bs[(wn * 64 + n * 16 + ro) * 32 + ko];
#pragma unroll
        for (int m = 0; m < 4; ++m)
#pragma unroll
            for (int n = 0; n < 4; ++n)
                acc[m][n] = __builtin_amdgcn_mfma_f32_16x16x32_bf16(af[m], bf[n], acc[m][n], 0, 0, 0);
    }

    // epilogue: C/D layout col=lane&15, row=(lane>>4)*4+j
#pragma unroll
    for (int m = 0; m < 4; ++m) {
        const int grow_base = row0 + wm * 64 + m * 16 + (lane >> 4) * 4;
#pragma unroll
        for (int n = 0; n < 4; ++n) {
            const int gcol = col0 + wn * 64 + n * 16 + (lane & 15);
            const float bv = b1[gcol];
#pragma unroll
            for (int j = 0; j < 4; ++j) {
                const int grow = grow_base + j;
                const float v = acc[m][n][j] + bv;
                const float sp = (v > 20.f) ? v : log1pf(expf(v));
                y[(size_t)grow * 1024 + gcol] = x[(size_t)grow * 1024 + gcol] * sp * cb[grow];
            }
        }
    }
}

extern "C" void kernel_launch(void* const* d_in, const int* in_sizes, int n_in,
                              void* d_out, int out_size, void* d_ws, size_t ws_size,
                              hipStream_t stream) {
    const float* x  = (const float*)d_in[0];
    const float* W1 = (const float*)d_in[1];
    const float* b1 = (const float*)d_in[2];
    const float* W2 = (const float*)d_in[3];
    const float* b2 = (const float*)d_in[4];
    const float* W3 = (const float*)d_in[5];
    const float* b3 = (const float*)d_in[6];
    // d_in[7] (A) is a dead parameter in the reference (multiplied by zeros)

    float* y = (float*)d_out;

    unsigned short* xb  = (unsigned short*)d_ws;                 // 16 MB
    unsigned short* w1b = xb + (size_t)8192 * 1024;              // 2 MB
    unsigned short* w2b = w1b + (size_t)1024 * 1024;             // 32 KB
    unsigned short* w3b = w2b + (size_t)16 * 1024;               // 32 KB
    float* cbuf = (float*)(w3b + (size_t)16 * 1024);             // 32 KB

    convert_w<<<1056, 256, 0, stream>>>(W1, W2, W3, w1b, w2b, w3b);
    cb_kernel<<<512, 256, 0, stream>>>(x, w2b, w3b, b2, b3, xb, cbuf);
    gemm_kernel<<<dim3(8, 64), 256, 0, stream>>>(xb, w1b, b1, x, cbuf, y);
}

// Round 3
// 57.628 us; speedup vs baseline: 4.0894x; 1.4856x over previous
//
#include <hip/hip_runtime.h>
#include <hip/hip_bf16.h>
#include <stdint.h>

// ---------- types ----------
typedef __attribute__((ext_vector_type(8))) short short8;     // 8 bf16 (4 VGPRs) MFMA A/B frag
typedef __attribute__((ext_vector_type(4))) float f32x4;      // MFMA C/D frag
typedef __attribute__((ext_vector_type(4))) unsigned short us4;

static __device__ __forceinline__ unsigned short f2bf(float f) {
    union { float f; uint32_t u; } v; v.f = f;
    uint32_t u = v.u;
    uint32_t r = u + 0x7FFFu + ((u >> 16) & 1u);   // round-to-nearest-even
    return (unsigned short)(r >> 16);
}
static __device__ __forceinline__ float bf2f(unsigned short h) {
    union { uint32_t u; float f; } v; v.u = ((uint32_t)h) << 16;
    return v.f;
}

static __device__ __forceinline__ short8 cvt8(float4 a, float4 b) {
    short8 r;
    r[0] = (short)f2bf(a.x); r[1] = (short)f2bf(a.y);
    r[2] = (short)f2bf(a.z); r[3] = (short)f2bf(a.w);
    r[4] = (short)f2bf(b.x); r[5] = (short)f2bf(b.y);
    r[6] = (short)f2bf(b.z); r[7] = (short)f2bf(b.w);
    return r;
}

// ---------- kernel 0: convert W1 / W2 / W3 f32 -> bf16 ----------
__global__ __launch_bounds__(256) void convert_w(const float* __restrict__ w1,
                                                 const float* __restrict__ w2,
                                                 const float* __restrict__ w3,
                                                 unsigned short* __restrict__ o1,
                                                 unsigned short* __restrict__ o2,
                                                 unsigned short* __restrict__ o3) {
    int b = blockIdx.x;
    const float* src; unsigned short* dst; int idx;
    if (b < 1024)      { src = w1; dst = o1; idx = b * 256 + threadIdx.x; }
    else if (b < 1040) { src = w2; dst = o2; idx = (b - 1024) * 256 + threadIdx.x; }
    else               { src = w3; dst = o3; idx = (b - 1040) * 256 + threadIdx.x; }
    float4 v = ((const float4*)src)[idx];
    us4 r = { f2bf(v.x), f2bf(v.y), f2bf(v.z), f2bf(v.w) };
    *(us4*)&dst[(size_t)idx * 4] = r;
}

// ---------- kernel 1: cb[row] = sum_n (x@W2^T + b2)*(x@W3^T + b3), + x -> bf16 ----------
__global__ __launch_bounds__(256) void cb_kernel(
    const float* __restrict__ x,            // [8192][1024]
    const unsigned short* __restrict__ w2b, // [16][1024] bf16
    const unsigned short* __restrict__ w3b, // [16][1024] bf16
    const float* __restrict__ b2,           // [16]
    const float* __restrict__ b3,           // [16]
    unsigned short* __restrict__ xb,        // out: [8192][1024] bf16
    float* __restrict__ cbo)                // out: [8192]
{
    __shared__ float red[4][2][16][16];     // [wave][B/C][row][n] = 8 KB

    const int t = threadIdx.x;
    const int wave = t >> 6, lane = t & 63;
    const int r0 = blockIdx.x * 16;
    const int rrow = lane & 15;
    const int klane = (lane >> 4) * 8;
    const size_t xrow = (size_t)(r0 + rrow) * 1024;
    const int k0 = wave * 256;

    f32x4 accB = {0.f, 0.f, 0.f, 0.f};
    f32x4 accC = {0.f, 0.f, 0.f, 0.f};

#pragma unroll
    for (int ks = 0; ks < 256; ks += 32) {
        const int k = k0 + ks + klane;
        float4 xa = *(const float4*)&x[xrow + k];
        float4 xc = *(const float4*)&x[xrow + k + 4];
        short8 af = cvt8(xa, xc);
        *(short8*)&xb[xrow + k] = af;
        short8 w2f = *(const short8*)&w2b[(size_t)rrow * 1024 + k];
        short8 w3f = *(const short8*)&w3b[(size_t)rrow * 1024 + k];
        accB = __builtin_amdgcn_mfma_f32_16x16x32_bf16(af, w2f, accB, 0, 0, 0);
        accC = __builtin_amdgcn_mfma_f32_16x16x32_bf16(af, w3f, accC, 0, 0, 0);
    }

#pragma unroll
    for (int j = 0; j < 4; ++j) {
        red[wave][0][(lane >> 4) * 4 + j][lane & 15] = accB[j];
        red[wave][1][(lane >> 4) * 4 + j][lane & 15] = accC[j];
    }
    __syncthreads();

    if (wave == 0) {
        const int n = lane & 15;
        const float b2v = b2[n], b3v = b3[n];
        float prod[4];
#pragma unroll
        for (int j = 0; j < 4; ++j) {
            const int row = (lane >> 4) * 4 + j;
            float Bv = red[0][0][row][n] + red[1][0][row][n]
                     + red[2][0][row][n] + red[3][0][row][n] + b2v;
            float Cv = red[0][1][row][n] + red[1][1][row][n]
                     + red[2][1][row][n] + red[3][1][row][n] + b3v;
            prod[j] = Bv * Cv;
        }
#pragma unroll
        for (int off = 1; off < 16; off <<= 1)
#pragma unroll
            for (int j = 0; j < 4; ++j)
                prod[j] += __shfl_xor(prod[j], off, 64);
        if ((lane & 15) == 0) {
#pragma unroll
            for (int j = 0; j < 4; ++j)
                cbo[r0 + (lane >> 4) * 4 + j] = prod[j];
        }
    }
}

// ---------- kernel 2: delta GEMM + fused epilogue ----------
// 128x128 tile, BK=64 (128B rows), double-buffered LDS, XOR-swizzled slots.
// Swizzle involution: 16B slot s at row r lives at linear slot s ^ (r&7).
// Write side: pre-swizzled GLOBAL source, linear global_load_lds dest (rule 21).
__global__ __launch_bounds__(256, 2) void gemm_kernel(
    const unsigned short* __restrict__ xb,   // [8192][1024] bf16
    const unsigned short* __restrict__ w1b,  // [1024][1024] bf16 (N x K)
    const float* __restrict__ b1,            // [1024]
    const float* __restrict__ cb,            // [8192]
    float* __restrict__ y)                   // [8192][1024] f32
{
    __shared__ unsigned short As[2][128 * 64];
    __shared__ unsigned short Bs[2][128 * 64];

    const int t = threadIdx.x;
    const int wid = t >> 6, lane = t & 63;
    const int wm = wid >> 1, wn = wid & 1;
    const int row0 = blockIdx.y * 128;
    const int col0 = blockIdx.x * 128;

    const int lrow = lane >> 3;              // 0..7 (row within 8-row group)
    const int gslot = (lane & 7) ^ lrow;     // pre-swizzled 16B slot in global

    f32x4 acc[4][4];
#pragma unroll
    for (int m = 0; m < 4; ++m)
#pragma unroll
        for (int n = 0; n < 4; ++n)
            acc[m][n] = (f32x4){0.f, 0.f, 0.f, 0.f};

    // stage K-tile (elem offset kt) into buffer b: 16KB A + 16KB B, 4 rounds x 4 waves
    auto STAGE = [&](int b, int kt) {
#pragma unroll
        for (int p = 0; p < 4; ++p) {
            const int grp = p * 4 + wid;            // 0..15 -> 8 rows each
            const int row = grp * 8 + lrow;         // 0..127
            const int gc = kt + gslot * 8;          // swizzled source column
            const unsigned short* ga = &xb[(size_t)(row0 + row) * 1024 + gc];
            const unsigned short* gb = &w1b[(size_t)(col0 + row) * 1024 + gc];
            __builtin_amdgcn_global_load_lds(
                (const __attribute__((address_space(1))) void*)ga,
                (__attribute__((address_space(3))) void*)&As[b][grp * 512 + lane * 8], 16, 0, 0);
            __builtin_amdgcn_global_load_lds(
                (const __attribute__((address_space(1))) void*)gb,
                (__attribute__((address_space(3))) void*)&Bs[b][grp * 512 + lane * 8], 16, 0, 0);
        }
    };

    STAGE(0, 0);
    __syncthreads();   // drain vmcnt(0) before first read

    const int ro = lane & 15;
    const int sh = lane >> 4;                // 0..3

    for (int tk = 0; tk < 16; ++tk) {
        const int cur = tk & 1;
        if (tk + 1 < 16) STAGE(cur ^ 1, (tk + 1) * 64);   // overlap with compute

        short8 af[2][4], bfr[2][4];
#pragma unroll
        for (int ks = 0; ks < 2; ++ks) {
            const int s = ks * 4 + sh;       // 16B slot within 128B row
#pragma unroll
            for (int m = 0; m < 4; ++m) {
                const int ar = wm * 64 + m * 16 + ro;
                af[ks][m]  = *(const short8*)&As[cur][ar * 64 + ((s ^ (ro & 7)) << 3)];
                const int br = wn * 64 + m * 16 + ro;
                bfr[ks][m] = *(const short8*)&Bs[cur][br * 64 + ((s ^ (ro & 7)) << 3)];
            }
        }
#pragma unroll
        for (int ks = 0; ks < 2; ++ks)
#pragma unroll
            for (int m = 0; m < 4; ++m)
#pragma unroll
                for (int n = 0; n < 4; ++n)
                    acc[m][n] = __builtin_amdgcn_mfma_f32_16x16x32_bf16(af[ks][m], bfr[ks][n], acc[m][n], 0, 0, 0);

        __syncthreads();   // drains this iter's STAGE (vmcnt 0) + guards buffer reuse
    }

    // epilogue: C/D layout col=lane&15, row=(lane>>4)*4+j
#pragma unroll
    for (int m = 0; m < 4; ++m) {
        const int grow_base = row0 + wm * 64 + m * 16 + (lane >> 4) * 4;
#pragma unroll
        for (int n = 0; n < 4; ++n) {
            const int gcol = col0 + wn * 64 + n * 16 + (lane & 15);
            const float bv = b1[gcol];
#pragma unroll
            for (int j = 0; j < 4; ++j) {
                const int grow = grow_base + j;
                const float v = acc[m][n][j] + bv;
                const float sp = (v > 15.f) ? v : __logf(1.f + __expf(v));
                const size_t off = (size_t)grow * 1024 + gcol;
                y[off] = bf2f(xb[off]) * sp * cb[grow];
            }
        }
    }
}

extern "C" void kernel_launch(void* const* d_in, const int* in_sizes, int n_in,
                              void* d_out, int out_size, void* d_ws, size_t ws_size,
                              hipStream_t stream) {
    const float* x  = (const float*)d_in[0];
    const float* W1 = (const float*)d_in[1];
    const float* b1 = (const float*)d_in[2];
    const float* W2 = (const float*)d_in[3];
    const float* b2 = (const float*)d_in[4];
    const float* W3 = (const float*)d_in[5];
    const float* b3 = (const float*)d_in[6];
    // d_in[7] (A) is a dead parameter in the reference (multiplied by zeros)

    float* y = (float*)d_out;

    unsigned short* xb  = (unsigned short*)d_ws;                 // 16 MB
    unsigned short* w1b = xb + (size_t)8192 * 1024;              // 2 MB
    unsigned short* w2b = w1b + (size_t)1024 * 1024;             // 32 KB
    unsigned short* w3b = w2b + (size_t)16 * 1024;               // 32 KB
    float* cbuf = (float*)(w3b + (size_t)16 * 1024);             // 32 KB

    convert_w<<<1056, 256, 0, stream>>>(W1, W2, W3, w1b, w2b, w3b);
    cb_kernel<<<512, 256, 0, stream>>>(x, w2b, w3b, b2, b3, xb, cbuf);
    gemm_kernel<<<dim3(8, 64), 256, 0, stream>>>(xb, w1b, b1, cbuf, y);
}

// Round 4
// 52.442 us; speedup vs baseline: 4.4938x; 1.0989x over previous
//
#include <hip/hip_runtime.h>
#include <hip/hip_bf16.h>
#include <stdint.h>

// ---------- types ----------
typedef __attribute__((ext_vector_type(8))) short short8;     // 8 bf16 (4 VGPRs) MFMA A/B frag
typedef __attribute__((ext_vector_type(4))) float f32x4;      // MFMA C/D frag
typedef __attribute__((ext_vector_type(4))) unsigned short us4;

static __device__ __forceinline__ unsigned short f2bf(float f) {
    union { float f; uint32_t u; } v; v.f = f;
    uint32_t u = v.u;
    uint32_t r = u + 0x7FFFu + ((u >> 16) & 1u);   // round-to-nearest-even
    return (unsigned short)(r >> 16);
}
static __device__ __forceinline__ float bf2f(unsigned short h) {
    union { uint32_t u; float f; } v; v.u = ((uint32_t)h) << 16;
    return v.f;
}

static __device__ __forceinline__ short8 cvt8(float4 a, float4 b) {
    short8 r;
    r[0] = (short)f2bf(a.x); r[1] = (short)f2bf(a.y);
    r[2] = (short)f2bf(a.z); r[3] = (short)f2bf(a.w);
    r[4] = (short)f2bf(b.x); r[5] = (short)f2bf(b.y);
    r[6] = (short)f2bf(b.z); r[7] = (short)f2bf(b.w);
    return r;
}

// ---------- kernel 0: convert W1 / W2 / W3 f32 -> bf16 ----------
__global__ __launch_bounds__(256) void convert_w(const float* __restrict__ w1,
                                                 const float* __restrict__ w2,
                                                 const float* __restrict__ w3,
                                                 unsigned short* __restrict__ o1,
                                                 unsigned short* __restrict__ o2,
                                                 unsigned short* __restrict__ o3) {
    int b = blockIdx.x;
    const float* src; unsigned short* dst; int idx;
    if (b < 1024)      { src = w1; dst = o1; idx = b * 256 + threadIdx.x; }
    else if (b < 1040) { src = w2; dst = o2; idx = (b - 1024) * 256 + threadIdx.x; }
    else               { src = w3; dst = o3; idx = (b - 1040) * 256 + threadIdx.x; }
    float4 v = ((const float4*)src)[idx];
    us4 r = { f2bf(v.x), f2bf(v.y), f2bf(v.z), f2bf(v.w) };
    *(us4*)&dst[(size_t)idx * 4] = r;
}

// ---------- kernel 1: cb[row] = sum_n (x@W2^T + b2)*(x@W3^T + b3), + x -> bf16 ----------
__global__ __launch_bounds__(256) void cb_kernel(
    const float* __restrict__ x,            // [8192][1024]
    const unsigned short* __restrict__ w2b, // [16][1024] bf16
    const unsigned short* __restrict__ w3b, // [16][1024] bf16
    const float* __restrict__ b2,           // [16]
    const float* __restrict__ b3,           // [16]
    unsigned short* __restrict__ xb,        // out: [8192][1024] bf16
    float* __restrict__ cbo)                // out: [8192]
{
    __shared__ float red[4][2][16][16];     // [wave][B/C][row][n] = 8 KB

    const int t = threadIdx.x;
    const int wave = t >> 6, lane = t & 63;
    const int r0 = blockIdx.x * 16;
    const int rrow = lane & 15;
    const int klane = (lane >> 4) * 8;
    const size_t xrow = (size_t)(r0 + rrow) * 1024;
    const int k0 = wave * 256;

    f32x4 accB = {0.f, 0.f, 0.f, 0.f};
    f32x4 accC = {0.f, 0.f, 0.f, 0.f};

#pragma unroll
    for (int ks = 0; ks < 256; ks += 32) {
        const int k = k0 + ks + klane;
        float4 xa = *(const float4*)&x[xrow + k];
        float4 xc = *(const float4*)&x[xrow + k + 4];
        short8 af = cvt8(xa, xc);
        *(short8*)&xb[xrow + k] = af;
        short8 w2f = *(const short8*)&w2b[(size_t)rrow * 1024 + k];
        short8 w3f = *(const short8*)&w3b[(size_t)rrow * 1024 + k];
        accB = __builtin_amdgcn_mfma_f32_16x16x32_bf16(af, w2f, accB, 0, 0, 0);
        accC = __builtin_amdgcn_mfma_f32_16x16x32_bf16(af, w3f, accC, 0, 0, 0);
    }

#pragma unroll
    for (int j = 0; j < 4; ++j) {
        red[wave][0][(lane >> 4) * 4 + j][lane & 15] = accB[j];
        red[wave][1][(lane >> 4) * 4 + j][lane & 15] = accC[j];
    }
    __syncthreads();

    if (wave == 0) {
        const int n = lane & 15;
        const float b2v = b2[n], b3v = b3[n];
        float prod[4];
#pragma unroll
        for (int j = 0; j < 4; ++j) {
            const int row = (lane >> 4) * 4 + j;
            float Bv = red[0][0][row][n] + red[1][0][row][n]
                     + red[2][0][row][n] + red[3][0][row][n] + b2v;
            float Cv = red[0][1][row][n] + red[1][1][row][n]
                     + red[2][1][row][n] + red[3][1][row][n] + b3v;
            prod[j] = Bv * Cv;
        }
#pragma unroll
        for (int off = 1; off < 16; off <<= 1)
#pragma unroll
            for (int j = 0; j < 4; ++j)
                prod[j] += __shfl_xor(prod[j], off, 64);
        if ((lane & 15) == 0) {
#pragma unroll
            for (int j = 0; j < 4; ++j)
                cbo[r0 + (lane >> 4) * 4 + j] = prod[j];
        }
    }
}

// ---------- kernel 2: delta GEMM + fused epilogue ----------
// 128x128 tile, BK=64, double-buffered LDS, XOR-swizzled slots, XCD row-chunk remap.
__global__ __launch_bounds__(256, 2) void gemm_kernel(
    const unsigned short* __restrict__ xb,   // [8192][1024] bf16
    const unsigned short* __restrict__ w1b,  // [1024][1024] bf16 (N x K)
    const float* __restrict__ b1,            // [1024]
    const float* __restrict__ cb,            // [8192]
    float* __restrict__ y)                   // [8192][1024] f32
{
    __shared__ unsigned short As[2][128 * 64];
    __shared__ unsigned short Bs[2][128 * 64];

    // XCD row-chunk remap: default dispatch sends wg%8 -> XCD (round robin).
    // Give XCD k the 64 blocks covering rows [8k,8k+8) x all 8 col-blocks, so
    // each A-tile (256KB) is fetched once into that XCD's L2 and reused 8x,
    // and w1b (2MB) stays L2-resident. Bijective: 512 = 8 * 64.
    const int wg = blockIdx.x;
    const int nid = (wg & 7) * 64 + (wg >> 3);
    const int row0 = (nid >> 3) * 128;
    const int col0 = (nid & 7) * 128;

    const int t = threadIdx.x;
    const int wid = t >> 6, lane = t & 63;
    const int wm = wid >> 1, wn = wid & 1;

    const int lrow = lane >> 3;              // 0..7 (row within 8-row group)
    const int gslot = (lane & 7) ^ lrow;     // pre-swizzled 16B slot in global

    f32x4 acc[4][4];
#pragma unroll
    for (int m = 0; m < 4; ++m)
#pragma unroll
        for (int n = 0; n < 4; ++n)
            acc[m][n] = (f32x4){0.f, 0.f, 0.f, 0.f};

    auto STAGE = [&](int b, int kt) {
#pragma unroll
        for (int p = 0; p < 4; ++p) {
            const int grp = p * 4 + wid;            // 0..15 -> 8 rows each
            const int row = grp * 8 + lrow;         // 0..127
            const int gc = kt + gslot * 8;          // swizzled source column
            const unsigned short* ga = &xb[(size_t)(row0 + row) * 1024 + gc];
            const unsigned short* gb = &w1b[(size_t)(col0 + row) * 1024 + gc];
            __builtin_amdgcn_global_load_lds(
                (const __attribute__((address_space(1))) void*)ga,
                (__attribute__((address_space(3))) void*)&As[b][grp * 512 + lane * 8], 16, 0, 0);
            __builtin_amdgcn_global_load_lds(
                (const __attribute__((address_space(1))) void*)gb,
                (__attribute__((address_space(3))) void*)&Bs[b][grp * 512 + lane * 8], 16, 0, 0);
        }
    };

    STAGE(0, 0);
    __syncthreads();   // drain vmcnt(0) before first read

    const int ro = lane & 15;
    const int sh = lane >> 4;                // 0..3

    for (int tk = 0; tk < 16; ++tk) {
        const int cur = tk & 1;
        if (tk + 1 < 16) STAGE(cur ^ 1, (tk + 1) * 64);   // overlap with compute

        short8 af[2][4], bfr[2][4];
#pragma unroll
        for (int ks = 0; ks < 2; ++ks) {
            const int s = ks * 4 + sh;       // 16B slot within 128B row
#pragma unroll
            for (int m = 0; m < 4; ++m) {
                const int ar = wm * 64 + m * 16 + ro;
                af[ks][m]  = *(const short8*)&As[cur][ar * 64 + ((s ^ (ro & 7)) << 3)];
                const int br = wn * 64 + m * 16 + ro;
                bfr[ks][m] = *(const short8*)&Bs[cur][br * 64 + ((s ^ (ro & 7)) << 3)];
            }
        }
#pragma unroll
        for (int ks = 0; ks < 2; ++ks)
#pragma unroll
            for (int m = 0; m < 4; ++m)
#pragma unroll
                for (int n = 0; n < 4; ++n)
                    acc[m][n] = __builtin_amdgcn_mfma_f32_16x16x32_bf16(af[ks][m], bfr[ks][n], acc[m][n], 0, 0, 0);

        __syncthreads();   // drains this iter's STAGE (vmcnt 0) + guards buffer reuse
    }

    // epilogue: C/D layout col=lane&15, row=(lane>>4)*4+j
#pragma unroll
    for (int m = 0; m < 4; ++m) {
        const int grow_base = row0 + wm * 64 + m * 16 + (lane >> 4) * 4;
#pragma unroll
        for (int n = 0; n < 4; ++n) {
            const int gcol = col0 + wn * 64 + n * 16 + (lane & 15);
            const float bv = b1[gcol];
#pragma unroll
            for (int j = 0; j < 4; ++j) {
                const int grow = grow_base + j;
                const float v = acc[m][n][j] + bv;
                const float sp = (v > 15.f) ? v : __logf(1.f + __expf(v));
                const size_t off = (size_t)grow * 1024 + gcol;
                y[off] = bf2f(xb[off]) * sp * cb[grow];
            }
        }
    }
}

extern "C" void kernel_launch(void* const* d_in, const int* in_sizes, int n_in,
                              void* d_out, int out_size, void* d_ws, size_t ws_size,
                              hipStream_t stream) {
    const float* x  = (const float*)d_in[0];
    const float* W1 = (const float*)d_in[1];
    const float* b1 = (const float*)d_in[2];
    const float* W2 = (const float*)d_in[3];
    const float* b2 = (const float*)d_in[4];
    const float* W3 = (const float*)d_in[5];
    const float* b3 = (const float*)d_in[6];
    // d_in[7] (A) is a dead parameter in the reference (multiplied by zeros)

    float* y = (float*)d_out;

    unsigned short* xb  = (unsigned short*)d_ws;                 // 16 MB
    unsigned short* w1b = xb + (size_t)8192 * 1024;              // 2 MB
    unsigned short* w2b = w1b + (size_t)1024 * 1024;             // 32 KB
    unsigned short* w3b = w2b + (size_t)16 * 1024;               // 32 KB
    float* cbuf = (float*)(w3b + (size_t)16 * 1024);             // 32 KB

    convert_w<<<1056, 256, 0, stream>>>(W1, W2, W3, w1b, w2b, w3b);
    cb_kernel<<<512, 256, 0, stream>>>(x, w2b, w3b, b2, b3, xb, cbuf);
    gemm_kernel<<<512, 256, 0, stream>>>(xb, w1b, b1, cbuf, y);
}

// Round 5
// 48.785 us; speedup vs baseline: 4.8307x; 1.0750x over previous
//
#include <hip/hip_runtime.h>
#include <hip/hip_bf16.h>
#include <stdint.h>

// ---------- types ----------
typedef __attribute__((ext_vector_type(8))) short short8;     // 8 bf16 (4 VGPRs) MFMA A/B frag
typedef __attribute__((ext_vector_type(4))) float f32x4;      // MFMA C/D frag
typedef __attribute__((ext_vector_type(4))) unsigned short us4;

static __device__ __forceinline__ unsigned short f2bf(float f) {
    union { float f; uint32_t u; } v; v.f = f;
    uint32_t u = v.u;
    uint32_t r = u + 0x7FFFu + ((u >> 16) & 1u);   // round-to-nearest-even
    return (unsigned short)(r >> 16);
}
static __device__ __forceinline__ float bf2f(unsigned short h) {
    union { uint32_t u; float f; } v; v.u = ((uint32_t)h) << 16;
    return v.f;
}

static __device__ __forceinline__ short8 cvt8(float4 a, float4 b) {
    short8 r;
    r[0] = (short)f2bf(a.x); r[1] = (short)f2bf(a.y);
    r[2] = (short)f2bf(a.z); r[3] = (short)f2bf(a.w);
    r[4] = (short)f2bf(b.x); r[5] = (short)f2bf(b.y);
    r[6] = (short)f2bf(b.z); r[7] = (short)f2bf(b.w);
    return r;
}

// ---------- kernel 0: convert W1 / W2 / W3 f32 -> bf16 ----------
__global__ __launch_bounds__(256) void convert_w(const float* __restrict__ w1,
                                                 const float* __restrict__ w2,
                                                 const float* __restrict__ w3,
                                                 unsigned short* __restrict__ o1,
                                                 unsigned short* __restrict__ o2,
                                                 unsigned short* __restrict__ o3) {
    int b = blockIdx.x;
    const float* src; unsigned short* dst; int idx;
    if (b < 1024)      { src = w1; dst = o1; idx = b * 256 + threadIdx.x; }
    else if (b < 1040) { src = w2; dst = o2; idx = (b - 1024) * 256 + threadIdx.x; }
    else               { src = w3; dst = o3; idx = (b - 1040) * 256 + threadIdx.x; }
    float4 v = ((const float4*)src)[idx];
    us4 r = { f2bf(v.x), f2bf(v.y), f2bf(v.z), f2bf(v.w) };
    *(us4*)&dst[(size_t)idx * 4] = r;
}

// ---------- kernel 1: cb[row] = sum_n (x@W2^T + b2)*(x@W3^T + b3), + x -> bf16 ----------
__global__ __launch_bounds__(256) void cb_kernel(
    const float* __restrict__ x,            // [8192][1024]
    const unsigned short* __restrict__ w2b, // [16][1024] bf16
    const unsigned short* __restrict__ w3b, // [16][1024] bf16
    const float* __restrict__ b2,           // [16]
    const float* __restrict__ b3,           // [16]
    unsigned short* __restrict__ xb,        // out: [8192][1024] bf16
    float* __restrict__ cbo)                // out: [8192]
{
    __shared__ float red[4][2][16][16];     // [wave][B/C][row][n] = 8 KB

    const int t = threadIdx.x;
    const int wave = t >> 6, lane = t & 63;
    const int r0 = blockIdx.x * 16;
    const int rrow = lane & 15;
    const int klane = (lane >> 4) * 8;
    const size_t xrow = (size_t)(r0 + rrow) * 1024;
    const int k0 = wave * 256;

    f32x4 accB = {0.f, 0.f, 0.f, 0.f};
    f32x4 accC = {0.f, 0.f, 0.f, 0.f};

#pragma unroll
    for (int ks = 0; ks < 256; ks += 32) {
        const int k = k0 + ks + klane;
        float4 xa = *(const float4*)&x[xrow + k];
        float4 xc = *(const float4*)&x[xrow + k + 4];
        short8 af = cvt8(xa, xc);
        *(short8*)&xb[xrow + k] = af;
        short8 w2f = *(const short8*)&w2b[(size_t)rrow * 1024 + k];
        short8 w3f = *(const short8*)&w3b[(size_t)rrow * 1024 + k];
        accB = __builtin_amdgcn_mfma_f32_16x16x32_bf16(af, w2f, accB, 0, 0, 0);
        accC = __builtin_amdgcn_mfma_f32_16x16x32_bf16(af, w3f, accC, 0, 0, 0);
    }

#pragma unroll
    for (int j = 0; j < 4; ++j) {
        red[wave][0][(lane >> 4) * 4 + j][lane & 15] = accB[j];
        red[wave][1][(lane >> 4) * 4 + j][lane & 15] = accC[j];
    }
    __syncthreads();

    if (wave == 0) {
        const int n = lane & 15;
        const float b2v = b2[n], b3v = b3[n];
        float prod[4];
#pragma unroll
        for (int j = 0; j < 4; ++j) {
            const int row = (lane >> 4) * 4 + j;
            float Bv = red[0][0][row][n] + red[1][0][row][n]
                     + red[2][0][row][n] + red[3][0][row][n] + b2v;
            float Cv = red[0][1][row][n] + red[1][1][row][n]
                     + red[2][1][row][n] + red[3][1][row][n] + b3v;
            prod[j] = Bv * Cv;
        }
#pragma unroll
        for (int off = 1; off < 16; off <<= 1)
#pragma unroll
            for (int j = 0; j < 4; ++j)
                prod[j] += __shfl_xor(prod[j], off, 64);
        if ((lane & 15) == 0) {
#pragma unroll
            for (int j = 0; j < 4; ++j)
                cbo[r0 + (lane >> 4) * 4 + j] = prod[j];
        }
    }
}

// ---------- kernel 2: delta GEMM + fused epilogue ----------
// 128x128 tile, BK=64, double-buffered LDS, XOR-swizzle, XCD row-chunk remap,
// counted vmcnt(8) pipeline (T4) + setprio around MFMA (T5).
__global__ __launch_bounds__(256, 2) void gemm_kernel(
    const unsigned short* __restrict__ xb,   // [8192][1024] bf16
    const unsigned short* __restrict__ w1b,  // [1024][1024] bf16 (N x K)
    const float* __restrict__ b1,            // [1024]
    const float* __restrict__ cb,            // [8192]
    float* __restrict__ y)                   // [8192][1024] f32
{
    __shared__ unsigned short As[2][128 * 64];
    __shared__ unsigned short Bs[2][128 * 64];

    // XCD row-chunk remap (bijective, 512 = 8 XCD * 64)
    const int wg = blockIdx.x;
    const int nid = (wg & 7) * 64 + (wg >> 3);
    const int row0 = (nid >> 3) * 128;
    const int col0 = (nid & 7) * 128;

    const int t = threadIdx.x;
    const int wid = t >> 6, lane = t & 63;
    const int wm = wid >> 1, wn = wid & 1;

    const int lrow = lane >> 3;              // 0..7 (row within 8-row group)
    const int gslot = (lane & 7) ^ lrow;     // pre-swizzled 16B slot in global

    f32x4 acc[4][4];
#pragma unroll
    for (int m = 0; m < 4; ++m)
#pragma unroll
        for (int n = 0; n < 4; ++n)
            acc[m][n] = (f32x4){0.f, 0.f, 0.f, 0.f};

    // Each wave issues exactly 8 global_load_lds per STAGE (4 rounds x A,B).
    auto STAGE = [&](int b, int kt) {
#pragma unroll
        for (int p = 0; p < 4; ++p) {
            const int grp = p * 4 + wid;            // 0..15 -> 8 rows each
            const int row = grp * 8 + lrow;         // 0..127
            const int gc = kt + gslot * 8;          // swizzled source column
            const unsigned short* ga = &xb[(size_t)(row0 + row) * 1024 + gc];
            const unsigned short* gb = &w1b[(size_t)(col0 + row) * 1024 + gc];
            __builtin_amdgcn_global_load_lds(
                (const __attribute__((address_space(1))) void*)ga,
                (__attribute__((address_space(3))) void*)&As[b][grp * 512 + lane * 8], 16, 0, 0);
            __builtin_amdgcn_global_load_lds(
                (const __attribute__((address_space(1))) void*)gb,
                (__attribute__((address_space(3))) void*)&Bs[b][grp * 512 + lane * 8], 16, 0, 0);
        }
    };

    STAGE(0, 0);
    asm volatile("s_waitcnt vmcnt(0)" ::: "memory");
    __builtin_amdgcn_s_barrier();
    __builtin_amdgcn_sched_barrier(0);

    const int ro = lane & 15;
    const int sh = lane >> 4;                // 0..3

    for (int tk = 0; tk < 16; ++tk) {
        const int cur = tk & 1;
        if (tk < 15) {
            STAGE(cur ^ 1, (tk + 1) * 64);           // 8 new loads in flight
            // current buffer's 8 loads (issued last iter) must be done;
            // keep the 8 just-issued next-buffer loads outstanding.
            asm volatile("s_waitcnt vmcnt(8)" ::: "memory");
        } else {
            asm volatile("s_waitcnt vmcnt(0)" ::: "memory");
        }
        __builtin_amdgcn_s_barrier();      // all waves' cur-loads have landed
        __builtin_amdgcn_sched_barrier(0); // no ds_read hoisting above barrier

        short8 af[2][4], bfr[2][4];
#pragma unroll
        for (int ks = 0; ks < 2; ++ks) {
            const int s = ks * 4 + sh;       // 16B slot within 128B row
#pragma unroll
            for (int m = 0; m < 4; ++m) {
                const int ar = wm * 64 + m * 16 + ro;
                af[ks][m]  = *(const short8*)&As[cur][ar * 64 + ((s ^ (ro & 7)) << 3)];
                const int br = wn * 64 + m * 16 + ro;
                bfr[ks][m] = *(const short8*)&Bs[cur][br * 64 + ((s ^ (ro & 7)) << 3)];
            }
        }
        __builtin_amdgcn_s_setprio(1);
#pragma unroll
        for (int ks = 0; ks < 2; ++ks)
#pragma unroll
            for (int m = 0; m < 4; ++m)
#pragma unroll
                for (int n = 0; n < 4; ++n)
                    acc[m][n] = __builtin_amdgcn_mfma_f32_16x16x32_bf16(af[ks][m], bfr[ks][n], acc[m][n], 0, 0, 0);
        __builtin_amdgcn_s_setprio(0);

        // WAR guard: our ds_reads of buf cur must complete before any wave's
        // next-iter STAGE overwrites it (next STAGE targets cur again at t+2,
        // but writes begin next iter).
        asm volatile("s_waitcnt lgkmcnt(0)" ::: "memory");
        __builtin_amdgcn_s_barrier();
        __builtin_amdgcn_sched_barrier(0);
    }

    // epilogue: C/D layout col=lane&15, row=(lane>>4)*4+j
#pragma unroll
    for (int m = 0; m < 4; ++m) {
        const int grow_base = row0 + wm * 64 + m * 16 + (lane >> 4) * 4;
#pragma unroll
        for (int n = 0; n < 4; ++n) {
            const int gcol = col0 + wn * 64 + n * 16 + (lane & 15);
            const float bv = b1[gcol];
#pragma unroll
            for (int j = 0; j < 4; ++j) {
                const int grow = grow_base + j;
                const float v = acc[m][n][j] + bv;
                const float sp = (v > 15.f) ? v : __logf(1.f + __expf(v));
                const size_t off = (size_t)grow * 1024 + gcol;
                y[off] = bf2f(xb[off]) * sp * cb[grow];
            }
        }
    }
}

extern "C" void kernel_launch(void* const* d_in, const int* in_sizes, int n_in,
                              void* d_out, int out_size, void* d_ws, size_t ws_size,
                              hipStream_t stream) {
    const float* x  = (const float*)d_in[0];
    const float* W1 = (const float*)d_in[1];
    const float* b1 = (const float*)d_in[2];
    const float* W2 = (const float*)d_in[3];
    const float* b2 = (const float*)d_in[4];
    const float* W3 = (const float*)d_in[5];
    const float* b3 = (const float*)d_in[6];
    // d_in[7] (A) is a dead parameter in the reference (multiplied by zeros)

    float* y = (float*)d_out;

    unsigned short* xb  = (unsigned short*)d_ws;                 // 16 MB
    unsigned short* w1b = xb + (size_t)8192 * 1024;              // 2 MB
    unsigned short* w2b = w1b + (size_t)1024 * 1024;             // 32 KB
    unsigned short* w3b = w2b + (size_t)16 * 1024;               // 32 KB
    float* cbuf = (float*)(w3b + (size_t)16 * 1024);             // 32 KB

    convert_w<<<1056, 256, 0, stream>>>(W1, W2, W3, w1b, w2b, w3b);
    cb_kernel<<<512, 256, 0, stream>>>(x, w2b, w3b, b2, b3, xb, cbuf);
    gemm_kernel<<<512, 256, 0, stream>>>(xb, w1b, b1, cbuf, y);
}